// Round 1
// baseline (412.008 us; speedup 1.0000x reference)
//
#include <hip/hip_runtime.h>

// out[row][j] = in[row][j] / sum_j(in[row][j]), inv->0 if non-finite.
// One 256-thread block per 1024-element row; each thread owns one float4.
// Row stays in registers between the reduction and the scaled store, so
// each input byte is read from HBM exactly once.
__global__ __launch_bounds__(256) void
normalizer_kernel(const float* __restrict__ in, float* __restrict__ out) {
    const size_t row = blockIdx.x;
    const float4* __restrict__ rin  = reinterpret_cast<const float4*>(in  + row * 1024);
    float4* __restrict__       rout = reinterpret_cast<float4*>      (out + row * 1024);

    float4 v = rin[threadIdx.x];

    // per-thread partial
    float s = (v.x + v.y) + (v.z + v.w);

    // wave-64 shuffle tree reduction
    #pragma unroll
    for (int off = 32; off > 0; off >>= 1)
        s += __shfl_down(s, off, 64);

    // combine the block's 4 waves through LDS
    __shared__ float wsum[4];
    const int wave = threadIdx.x >> 6;
    const int lane = threadIdx.x & 63;
    if (lane == 0) wsum[wave] = s;
    __syncthreads();

    const float total = (wsum[0] + wsum[1]) + (wsum[2] + wsum[3]);
    float inv = 1.0f / total;
    if (!isfinite(inv)) inv = 0.0f;   // remove_nan_inf semantics

    v.x *= inv; v.y *= inv; v.z *= inv; v.w *= inv;
    rout[threadIdx.x] = v;
}

extern "C" void kernel_launch(void* const* d_in, const int* in_sizes, int n_in,
                              void* d_out, int out_size, void* d_ws, size_t ws_size,
                              hipStream_t stream) {
    const float* adj = reinterpret_cast<const float*>(d_in[0]);
    float* out = reinterpret_cast<float*>(d_out);
    const int n_rows = in_sizes[0] / 1024;   // 2*32*1024 = 65536 rows
    normalizer_kernel<<<dim3(n_rows), dim3(256), 0, stream>>>(adj, out);
}